// Round 5
// baseline (318.678 us; speedup 1.0000x reference)
//
#include <hip/hip_runtime.h>
#include <hip/hip_bf16.h>

typedef __attribute__((ext_vector_type(4))) float f32x4;
typedef __attribute__((ext_vector_type(8))) short short8;
typedef __attribute__((ext_vector_type(2))) unsigned int uint2v;

#define S_DIM 2048
#define D_DIM 64
#define KB 128
#define NHEADS 32
#define QTILES 32
#define NJT 16
#define TILE_USHORT (D_DIM * KB)     // 8192 ushorts = 16KB per (head, jtile)

static __device__ __forceinline__ unsigned short f2bf(float x) {
    union { __hip_bfloat16 h; unsigned short u; } c;
    c.h = __float2bfloat16(x);
    return c.u;
}
static __device__ __forceinline__ float bf2f(unsigned short u) {
    union { unsigned int i; float f; } c;
    c.i = ((unsigned int)u) << 16;
    return c.f;
}

// ---------------------------------------------------------------------------
// Prepass: V [head][j][d] fp32 -> blob[head][jt] = Vt[d][j_local] bf16,
// plain row-major 256B rows (no swizzle; main kernel reads it to registers).
// ---------------------------------------------------------------------------
__global__ __launch_bounds__(256)
void prep_v(const float* __restrict__ V, unsigned short* __restrict__ blob)
{
    const int b = blockIdx.x, head = b >> 4, jt = b & 15;
    const int t = threadIdx.x, d = t & 63, jg = t >> 6;
    const float* src = V + ((size_t)head * S_DIM + (size_t)jt * KB + jg * 32) * D_DIM + d;
    unsigned short* dst = blob + (size_t)(head * NJT + jt) * TILE_USHORT + d * KB + jg * 32;
    #pragma unroll
    for (int h = 0; h < 4; ++h) {
        short8 w;
        #pragma unroll
        for (int e = 0; e < 8; ++e)
            w[e] = (short)f2bf(src[(size_t)(h * 8 + e) * D_DIM]);
        *(short8*)(dst + h * 8) = w;
    }
}

// ---------------------------------------------------------------------------
// Main: flash softmax(L)·V. KEY CHANGE vs R1-R4: p-loads are wave-CONTIGUOUS
// (each 32-lane half reads 512B of one L row) for DRAM page locality; exp'd
// bf16 P goes through a per-wave 4KB LDS patch (XOR-swizzled) to reach the
// MFMA A-fragment layout. V-fragments come register-direct from the L2-
// resident blob. No __syncthreads, no glds, no manual waitcnt — waves run
// free; compiler manages all waits.
// ---------------------------------------------------------------------------
__global__ __launch_bounds__(256, 3)
void attn_main(const float* __restrict__ L,
               const unsigned short* __restrict__ blob,
               float* __restrict__ O)
{
    __shared__ __align__(16) unsigned char plds[4][4096];   // per-wave patches

    const int tid  = threadIdx.x;
    const int wave = tid >> 6;
    const int lane = tid & 63;
    const int lr   = lane & 15;     // A row / B col / D col
    const int lg   = lane >> 4;     // k-group
    const int half = lane >> 5;     // p-load: which of the 2 rows per instr
    const int l5   = lane & 31;     // p-load: 16B slot within the 512B row-chunk

    // XCD swizzle: 32 Q-tiles of a head share one XCD's L2 (blob slice 256 KB)
    const int bid  = blockIdx.x;
    const int xcd  = bid & 7;
    const int ixd  = bid >> 3;
    const int head = xcd * (NHEADS / 8) + (ixd >> 5);
    const int qt   = ixd & (QTILES - 1);
    const int i0   = qt * 64 + wave * 16;

    // contiguous p-load base: instr k reads rows i0+2k / i0+2k+1, this lane's
    // 16B at float-col 4*l5 (+ t*KB per tile)
    const float* lw = L + ((size_t)head * S_DIM + (size_t)(i0 + half)) * S_DIM + 4 * l5;
    const unsigned short* hblob = blob + (size_t)head * NJT * TILE_USHORT;
    unsigned char* pw = &plds[wave][0];

    f32x4 acc[4] = {};
    float lsum = 0.0f;

    f32x4 pa[8], pb[8];
    #pragma unroll
    for (int k = 0; k < 8; ++k)
        pa[k] = *(const f32x4*)(lw + (size_t)(2 * k) * S_DIM);

    auto step = [&](int t, f32x4* cur, f32x4* nxt) {
        // 1. issue contiguous p-loads for tile t+1 (full-iter latency overlap)
        if (t + 1 < NJT) {
            const float* s = lw + (size_t)(t + 1) * KB;
            #pragma unroll
            for (int k = 0; k < 8; ++k)
                nxt[k] = *(const f32x4*)(s + (size_t)(2 * k) * S_DIM);
        }
        // 2. exp + bf16-pack + swizzled ds_write (per-wave patch, rows 2k+half)
        #pragma unroll
        for (int k = 0; k < 8; ++k) {
            const int row = 2 * k + half;
            float e0 = __expf(cur[k][0]), e1 = __expf(cur[k][1]);
            float e2 = __expf(cur[k][2]), e3 = __expf(cur[k][3]);
            uint2v wv;
            wv[0] = (unsigned)f2bf(e0) | ((unsigned)f2bf(e1) << 16);
            wv[1] = (unsigned)f2bf(e2) | ((unsigned)f2bf(e3) << 16);
            *(uint2v*)(pw + row * 256 + ((l5 * 8) ^ ((row & 7) << 4))) = wv;
        }
        // 3. read A-fragments back (swizzled, bank-balanced) + lsum from bf16
        short8 afr[4];
        #pragma unroll
        for (int c = 0; c < 4; ++c)
            afr[c] = *(const short8*)(pw + lr * 256 + (((c * 64) | (lg * 16)) ^ ((lr & 7) << 4)));
        #pragma unroll
        for (int c = 0; c < 4; ++c)
            #pragma unroll
            for (int e = 0; e < 8; ++e)
                lsum += bf2f((unsigned short)afr[c][e]);
        // 4. V-fragments register-direct from L2 blob + MFMA
        const unsigned short* tile = hblob + (size_t)t * TILE_USHORT;
        #pragma unroll
        for (int c = 0; c < 4; ++c) {
            #pragma unroll
            for (int n = 0; n < 4; ++n) {
                short8 bfr = *(const short8*)(tile + (n * 16 + lr) * KB + c * 32 + lg * 8);
                acc[n] = __builtin_amdgcn_mfma_f32_16x16x32_bf16(afr[c], bfr, acc[n], 0, 0, 0);
            }
        }
    };

    #pragma unroll
    for (int tt = 0; tt < NJT / 2; ++tt) {
        step(2 * tt,     pa, pb);
        step(2 * tt + 1, pb, pa);
    }

    // ---- epilogue: row sums (denominator consistent with bf16 numerator) ----
    lsum += __shfl_xor(lsum, 16);
    lsum += __shfl_xor(lsum, 32);
    #pragma unroll
    for (int r = 0; r < 4; ++r) {
        const float inv = 1.0f / __shfl(lsum, lg * 4 + r);
        float* orow = O + ((size_t)head * S_DIM + (size_t)(i0 + lg * 4 + r)) * D_DIM;
        #pragma unroll
        for (int n = 0; n < 4; ++n)
            orow[n * 16 + lr] = acc[n][r] * inv;
    }
}

extern "C" void kernel_launch(void* const* d_in, const int* in_sizes, int n_in,
                              void* d_out, int out_size, void* d_ws, size_t ws_size,
                              hipStream_t stream) {
    const float* v = (const float*)d_in[0];
    const float* l = (const float*)d_in[1];
    float* out     = (float*)d_out;
    unsigned short* blob = (unsigned short*)d_ws;   // 8 MB used

    prep_v<<<dim3(NHEADS * NJT), dim3(256), 0, stream>>>(v, blob);
    attn_main<<<dim3(NHEADS * QTILES), dim3(256), 0, stream>>>(l, blob, out);
}